// Round 1
// baseline (357.132 us; speedup 1.0000x reference)
//
#include <hip/hip_runtime.h>
#include <hip/hip_bf16.h>

#define BATCH 8
#define NPTS  131072
#define DIM   32
#define NLAB  33
#define BPB   128   // blocks per batch for the two streaming passes

// ws float layout
#define OFF_CNT   0                    // BATCH*NLAB = 264
#define OFF_SUM   264                  // BATCH*NLAB*DIM = 8448
#define OFF_HNG   (264 + 8448)         // 264
#define OFF_PULL  (264 + 8448 + 264)   // 8
#define OFF_PUSH  (OFF_PULL + 8)       // 8
#define WS_FLOATS (OFF_PUSH + 8)

// Pass 1: per-batch label counts and per-label embedding sums.
// LDS accumulator transposed [d][l] (stride 33) so bank = (d + l) % 32:
// random labels spread atomic traffic across banks.
__global__ __launch_bounds__(256) void pass1_kernel(
    const float* __restrict__ emb, const int* __restrict__ lab,
    float* __restrict__ gsum, float* __restrict__ gcnt) {
  const int b   = blockIdx.y;
  const int tid = threadIdx.x;
  __shared__ float s_sum[DIM * NLAB];
  __shared__ float s_cnt[NLAB];
  for (int i = tid; i < DIM * NLAB; i += 256) s_sum[i] = 0.f;
  if (tid < NLAB) s_cnt[tid] = 0.f;
  __syncthreads();

  const int sub   = tid >> 3;        // point slot within 32-point group
  const int lane8 = tid & 7;
  const int d0    = lane8 << 2;      // 4 dims per thread
  const size_t base = (size_t)b * NPTS;

  for (int p = blockIdx.x * 32 + sub; p < NPTS; p += BPB * 32) {
    const int l = lab[base + p];
    const float4 e = *(const float4*)(emb + (base + p) * DIM + d0);
    atomicAdd(&s_sum[(d0 + 0) * NLAB + l], e.x);
    atomicAdd(&s_sum[(d0 + 1) * NLAB + l], e.y);
    atomicAdd(&s_sum[(d0 + 2) * NLAB + l], e.z);
    atomicAdd(&s_sum[(d0 + 3) * NLAB + l], e.w);
    if (lane8 == 0) atomicAdd(&s_cnt[l], 1.0f);
  }
  __syncthreads();

  for (int i = tid; i < NLAB * DIM; i += 256) {
    const int l = i >> 5, d = i & 31;
    atomicAdd(&gsum[b * (NLAB * DIM) + i], s_sum[d * NLAB + l]);
  }
  if (tid < NLAB) atomicAdd(&gcnt[b * NLAB + tid], s_cnt[tid]);
}

// Pass 2: per-point distance-to-own-mean hinge, accumulated per label.
__global__ __launch_bounds__(256) void pass2_kernel(
    const float* __restrict__ emb, const int* __restrict__ lab,
    const float* __restrict__ gsum, const float* __restrict__ gcnt,
    float* __restrict__ ghinge) {
  const int b   = blockIdx.y;
  const int tid = threadIdx.x;
  __shared__ __align__(16) float s_mean[NLAB * DIM];  // [l][d]
  __shared__ float s_hinge[NLAB];

  for (int i = tid; i < NLAB * DIM; i += 256) {
    const int l = i >> 5;
    const float c = gcnt[b * NLAB + l];
    s_mean[i] = gsum[b * (NLAB * DIM) + i] / fmaxf(c, 1.0f);
  }
  if (tid < NLAB) s_hinge[tid] = 0.f;
  __syncthreads();

  const int sub   = tid >> 3;
  const int lane8 = tid & 7;
  const int d0    = lane8 << 2;
  const size_t base = (size_t)b * NPTS;
  const float4* smean4 = (const float4*)s_mean;

  for (int p = blockIdx.x * 32 + sub; p < NPTS; p += BPB * 32) {
    const int l = lab[base + p];
    const float4 e = *(const float4*)(emb + (base + p) * DIM + d0);
    const float4 m = smean4[l * 8 + lane8];
    const float dx = e.x - m.x, dy = e.y - m.y, dz = e.z - m.z, dw = e.w - m.w;
    float s = dx * dx + dy * dy + dz * dz + dw * dw;
    s += __shfl_xor(s, 1);
    s += __shfl_xor(s, 2);
    s += __shfl_xor(s, 4);
    if (lane8 == 0) {
      const float dist  = sqrtf(s + 1e-24f);
      const float hinge = fmaxf(dist - 0.1f, 0.f);
      atomicAdd(&s_hinge[l], hinge);
    }
  }
  __syncthreads();
  if (tid < NLAB) atomicAdd(&ghinge[b * NLAB + tid], s_hinge[tid]);
}

// Per-batch pull/push. One wave per batch, 8 blocks.
__global__ __launch_bounds__(64) void per_batch_kernel(
    const float* __restrict__ gsum, const float* __restrict__ gcnt,
    const float* __restrict__ ghinge,
    float* __restrict__ pullb, float* __restrict__ pushb) {
  const int b = blockIdx.x;
  const int t = threadIdx.x;
  __shared__ __align__(16) float s_mn[32 * 32];  // normalized means, labels 1..32

  float cnt = 0.f;
  int   pres = 0;
  if (t < 32) {
    const int l = t + 1;
    cnt  = gcnt[b * NLAB + l];
    pres = (cnt > 0.f) ? 1 : 0;
    const float inv = 1.f / fmaxf(cnt, 1.f);
    float v[DIM];
    float n2 = 0.f;
    for (int d = 0; d < DIM; d++) {
      v[d] = gsum[b * (NLAB * DIM) + l * DIM + d] * inv;
      n2  += v[d] * v[d];
    }
    const float scale = 1.f / fmaxf(sqrtf(n2), 1e-12f);
    for (int d = 0; d < DIM; d++) s_mn[t * DIM + d] = v[d] * scale;
  }
  const unsigned long long bal = __ballot(pres);
  const unsigned int pmask32 = (unsigned int)(bal & 0xFFFFFFFFull);
  const int n_inst = __popc(pmask32);

  // pull
  float seg = 0.f;
  if (t < 32) seg = ghinge[b * NLAB + t + 1] / fmaxf(cnt, 1.f);
  for (int m = 1; m < 64; m <<= 1) seg += __shfl_xor(seg, m);
  const float pull = seg / ((float)n_inst + 1e-6f);

  __syncthreads();

  // push: 32x32 upper-triangle pairs
  float hp_sum = 0.f, pm_sum = 0.f;
  for (int idx = t; idx < 1024; idx += 64) {
    const int i = idx >> 5, j = idx & 31;
    if (j > i && ((pmask32 >> i) & 1u) && ((pmask32 >> j) & 1u)) {
      const float4* a = (const float4*)(s_mn + i * DIM);
      const float4* c = (const float4*)(s_mn + j * DIM);
      float sq = 0.f;
      for (int q = 0; q < 8; q++) {
        const float4 av = a[q], cv = c[q];
        const float dx = av.x - cv.x, dy = av.y - cv.y;
        const float dz = av.z - cv.z, dw = av.w - cv.w;
        sq += dx * dx + dy * dy + dz * dz + dw * dw;
      }
      const float dmat = sqrtf(sq + 1e-24f);
      hp_sum += fmaxf(1.0f - dmat, 0.f);   // 2*DELTA_D = 1.0
      pm_sum += 1.f;
    }
  }
  for (int m = 1; m < 64; m <<= 1) {
    hp_sum += __shfl_xor(hp_sum, m);
    pm_sum += __shfl_xor(pm_sum, m);
  }
  const float push = (n_inst > 1) ? hp_sum / (pm_sum + 1e-6f) : 0.f;

  if (t == 0) { pullb[b] = pull; pushb[b] = push; }
}

__global__ __launch_bounds__(64) void combine_kernel(
    const float* __restrict__ pullb, const float* __restrict__ pushb,
    float* __restrict__ out) {
  const int t = threadIdx.x;
  float pl = (t < BATCH) ? pullb[t] : 0.f;
  float ps = (t < BATCH) ? pushb[t] : 0.f;
  for (int m = 1; m < 64; m <<= 1) {
    pl += __shfl_xor(pl, m);
    ps += __shfl_xor(ps, m);
  }
  if (t == 0) {
    const float pull = pl / (float)BATCH;
    const float push = ps / (float)BATCH;
    out[0] = pull + push;
    out[1] = pull;
    out[2] = push;
  }
}

extern "C" void kernel_launch(void* const* d_in, const int* in_sizes, int n_in,
                              void* d_out, int out_size, void* d_ws, size_t ws_size,
                              hipStream_t stream) {
  const float* emb = (const float*)d_in[0];
  const int*   lab = (const int*)d_in[1];
  float* out = (float*)d_out;
  float* ws  = (float*)d_ws;

  float* gcnt   = ws + OFF_CNT;
  float* gsum   = ws + OFF_SUM;
  float* ghinge = ws + OFF_HNG;
  float* pullb  = ws + OFF_PULL;
  float* pushb  = ws + OFF_PUSH;

  hipMemsetAsync(d_ws, 0, WS_FLOATS * sizeof(float), stream);

  dim3 grid(BPB, BATCH);
  pass1_kernel<<<grid, 256, 0, stream>>>(emb, lab, gsum, gcnt);
  pass2_kernel<<<grid, 256, 0, stream>>>(emb, lab, gsum, gcnt, ghinge);
  per_batch_kernel<<<BATCH, 64, 0, stream>>>(gsum, gcnt, ghinge, pullb, pushb);
  combine_kernel<<<1, 64, 0, stream>>>(pullb, pushb, out);
}